// Round 10
// baseline (306.918 us; speedup 1.0000x reference)
//
#include <hip/hip_runtime.h>
#include <cstdint>

#pragma clang fp contract(off)

#define BS   128
#define NQ   900
#define NC   91
#define NQC  (NQ * NC)   // 81900
#define PRE  10000
#define POST 100
#define SEGA 8192
#define SEGB 4096
#define RUNSZ 4096
#define TBITS 13
#define TBINS (1 << TBITS)
#define TSHIFT (32 - TBITS)
#define WPRE 320                  // ceil(PRE/32) words for active bitmask
#define K_WIN 16

typedef unsigned long long ull;

__device__ __forceinline__ uint32_t fkey(float f) {
    uint32_t b = __float_as_uint(f);
    return (b & 0x80000000u) ? ~b : (b | 0x80000000u);
}
// defensive clamp: valid keys give q < NQ; turns capacity bugs into wrong-value not fault
__device__ __forceinline__ uint32_t qclamp(uint32_t q) { return (q < NQ) ? q : (NQ - 1); }

// ================= Single fused kernel: one block per image =================
// Phases: (0) 13-bit LDS histogram of fkey(logits)  (1) thresholds T_lo/T_hi via
// suffix scans (A: key>=T_hi, |A|<=8192; B: [T_lo,T_hi), |B|<=4096, rare 8-bit refine)
// (2) compact into LDS keys (3 runs of 4096, zero-padded)  (3) interleaved bitonic
// sort of the 3 runs (desc)  (4) LDS rank-merge of A-runs + B concat -> fidx, class
// hist, max coord  (5) class-bucket scatter  (6) windowed greedy NMS (16-wide,
// wave-parallel extraction + ballot conflict matrix). Cross-class suppression is
// provably impossible (offset bands: inter <= area/4 => IoU <= 1/3 < 0.7).
//
// LDS aliasing: [0,98304) keys (later: clist in [0,20000)); [98304,138304) fidx
// (earlier: hist 32KB + part 4KB + part2); [138304,152704) pred_boxes float4.
__global__ void __launch_bounds__(1024) k_fused(const float* __restrict__ logits,
                                                const float* __restrict__ pred_boxes,
                                                const float* __restrict__ target_sizes,
                                                float* __restrict__ out) {
    __shared__ __align__(16) unsigned char smem[152704];
    __shared__ uint32_t actw[WPRE];
    __shared__ uint32_t ccnt[NC], cstart[NC + 1], cfill[NC];
    __shared__ uint32_t smx[16];
    __shared__ uint32_t sCtrA, sCtrB;
    __shared__ uint32_t sTlo, sThi, sBlo, sCumAboveLo, sM, sM1;
    __shared__ float sOffD;
    __shared__ int   s_ncand;
    __shared__ int   s_cand[K_WIN];
    __shared__ float s_cx1[K_WIN], s_cy1[K_WIN], s_cx2[K_WIN], s_cy2[K_WIN], s_car[K_WIN];
    __shared__ int   s_ccl[K_WIN], s_cbs[K_WIN], s_cbe[K_WIN];

    ull*      KY   = (ull*)smem;                         // 12288 ull = 96 KB
    uint32_t* FI   = (uint32_t*)(smem + 98304);          // fidx: 10000 u32
    float4*   PBS  = (float4*)(smem + 138304);           // 900 float4
    uint32_t* HIST = FI;                                 // 8192 u32 (phases 0-2 only)
    uint32_t* part = FI + TBINS;                         // 1024 u32
    uint32_t* part2 = FI + TBINS + 1024;                 // 32 u32
    unsigned short* clist = (unsigned short*)smem;       // 10000 u16 (aliases KY, phase 5+)

    const int img = blockIdx.x;
    const int tid = threadIdx.x;
    const int lane = tid & 63;
    const float ih = target_sizes[img * 2 + 0];
    const float iw = target_sizes[img * 2 + 1];
    const float* pb = pred_boxes + (size_t)img * NQ * 4;
    const float* lg = logits + (size_t)img * NQC;

    // ---- Phase 0: histogram ----
    for (int i = tid; i < TBINS; i += 1024) HIST[i] = 0u;
    if (tid == 0) { sCtrA = 0u; sCtrB = 0u; }
    __syncthreads();
    const float4* lg4 = (const float4*)lg;
    for (int i = tid; i < NQC / 4; i += 1024) {
        float4 v = lg4[i];
        atomicAdd(&HIST[fkey(v.x) >> TSHIFT], 1u);
        atomicAdd(&HIST[fkey(v.y) >> TSHIFT], 1u);
        atomicAdd(&HIST[fkey(v.z) >> TSHIFT], 1u);
        atomicAdd(&HIST[fkey(v.w) >> TSHIFT], 1u);
    }
    __syncthreads();

    // ---- Phase 1: thresholds ----
    {
        uint32_t s = 0;
        int base = tid * (TBINS / 1024);
        for (int j = 0; j < TBINS / 1024; ++j) s += HIST[base + j];
        part[tid] = s;
    }
    __syncthreads();
    if (tid < 32) {
        uint32_t s2 = 0;
        for (int j = 0; j < 32; ++j) s2 += part[tid * 32 + j];
        part2[tid] = s2;
    }
    __syncthreads();
    if (tid == 0) {
        uint32_t cum = 0; int w = 31;
        for (; w > 0; --w) { if (cum + part2[w] >= PRE) break; cum += part2[w]; }
        int t = w * 32 + 31;
        for (; t > w * 32; --t) { if (cum + part[t] >= PRE) break; cum += part[t]; }
        int b = t * (TBINS / 1024) + (TBINS / 1024 - 1);
        for (; b > t * (TBINS / 1024); --b) { if (cum + HIST[b] >= PRE) break; cum += HIST[b]; }
        sBlo = (uint32_t)b;
        sCumAboveLo = cum;
        sM = cum + HIST[b];
        sTlo = ((uint32_t)b) << TSHIFT;
        uint32_t cum2 = 0; int w2 = 31;
        for (; w2 >= 0; --w2) { if (cum2 + part2[w2] > SEGA) break; cum2 += part2[w2]; }
        int t2 = w2 * 32 + 31;
        for (; t2 >= w2 * 32; --t2) { if (cum2 + part[t2] > SEGA) break; cum2 += part[t2]; }
        int b2 = t2 * (TBINS / 1024) + (TBINS / 1024 - 1);
        for (; b2 >= t2 * (TBINS / 1024); --b2) { if (cum2 + HIST[b2] > SEGA) break; cum2 += HIST[b2]; }
        sM1 = cum2;
        sThi = (b2 >= TBINS - 1) ? 0xFFFFFFFFu : (((uint32_t)(b2 + 1)) << TSHIFT);
    }
    __syncthreads();
    if (sM - sM1 > SEGB) {   // block-uniform rare fallback: refine Tlo by 8 bits
        uint32_t P = sBlo;
        for (int i = tid; i < 256; i += 1024) part[i] = 0u;
        __syncthreads();
        for (int i = tid; i < NQC / 4; i += 1024) {
            float4 v = lg4[i];
            uint32_t u;
            u = fkey(v.x); if ((u >> TSHIFT) == P) atomicAdd(&part[(u >> (TSHIFT - 8)) & 0xFFu], 1u);
            u = fkey(v.y); if ((u >> TSHIFT) == P) atomicAdd(&part[(u >> (TSHIFT - 8)) & 0xFFu], 1u);
            u = fkey(v.z); if ((u >> TSHIFT) == P) atomicAdd(&part[(u >> (TSHIFT - 8)) & 0xFFu], 1u);
            u = fkey(v.w); if ((u >> TSHIFT) == P) atomicAdd(&part[(u >> (TSHIFT - 8)) & 0xFFu], 1u);
        }
        __syncthreads();
        if (tid == 0) {
            uint32_t K = PRE - sCumAboveLo;
            uint32_t cum = 0; int x = 255;
            for (; x > 0; --x) { if (cum + part[x] >= K) break; cum += part[x]; }
            sTlo = (P << TSHIFT) | (((uint32_t)x) << (TSHIFT - 8));
        }
        __syncthreads();
    }
    const uint32_t Tlo = sTlo, Thi = sThi;

    // ---- Phase 2: compact into LDS keys (wave-ballot aggregated) ----
    for (int base = 0; base < NQC; base += 1024) {
        int i = base + tid;
        uint32_t u = 0u; bool a = false, b = false;
        if (i < NQC) {
            u = fkey(lg[i]);
            a = (u >= Thi);
            b = !a && (u >= Tlo);
        }
        ull ma = __ballot(a), mb = __ballot(b);
        uint32_t bA = (uint32_t)__popcll(ma & ((1ull << lane) - 1ull));
        uint32_t bB = (uint32_t)__popcll(mb & ((1ull << lane) - 1ull));
        uint32_t wA = 0u, wB = 0u;
        if (lane == 0) {
            if (ma) wA = atomicAdd(&sCtrA, (uint32_t)__popcll(ma));
            if (mb) wB = atomicAdd(&sCtrB, (uint32_t)__popcll(mb));
        }
        wA = __shfl(wA, 0, 64);
        wB = __shfl(wB, 0, 64);
        ull kv = ((ull)u << 32) | (ull)(0xFFFFFFFFu - (uint32_t)i);
        if (a) { uint32_t p = wA + bA; if (p < SEGA) KY[p] = kv; }
        if (b) { uint32_t p = wB + bB; if (p < SEGB) KY[SEGA + p] = kv; }
    }
    __syncthreads();
    uint32_t cntA = sCtrA; if (cntA > SEGA) cntA = SEGA;
    uint32_t cntB = sCtrB; if (cntB > SEGB) cntB = SEGB;
    for (int i = (int)cntA + tid; i < SEGA; i += 1024) KY[i] = 0ull;
    for (int i = (int)cntB + tid; i < SEGB; i += 1024) KY[SEGA + i] = 0ull;
    __syncthreads();

    // ---- Phase 3: interleaved bitonic sort of 3 runs of 4096 (desc) ----
    for (int k = 2; k <= RUNSZ; k <<= 1) {
        for (int j = k >> 1; j > 0; j >>= 1) {
            for (int t = tid; t < 3 * (RUNSZ / 2); t += 1024) {
                int run = t >> 11;
                int tt = t & (RUNSZ / 2 - 1);
                int i = ((tt & ~(j - 1)) << 1) | (tt & (j - 1));
                int ixj = i | j;
                int off = run * RUNSZ;
                ull a = KY[off + i], b = KY[off + ixj];
                bool sw = ((i & k) == 0) ? (a < b) : (a > b);
                if (sw) { KY[off + i] = b; KY[off + ixj] = a; }
            }
            __syncthreads();
        }
    }

    // ---- Phase 4: rank-merge A runs (LDS binary search), concat B; fidx/ccnt/max ----
    if (tid < NQ) PBS[tid] = ((const float4*)pb)[tid];
    for (int c = tid; c < NC; c += 1024) ccnt[c] = 0u;
    for (int wI = tid; wI < WPRE; wI += 1024) {
        int base = wI * 32;
        uint32_t m = 0xFFFFFFFFu;
        if (base + 32 > PRE) m = (base >= PRE) ? 0u : (0xFFFFFFFFu >> (base + 32 - PRE));
        actw[wI] = m;
    }
    __syncthreads();
    uint32_t lmx = 0u;
    #pragma unroll
    for (int k = 0; k < 8; ++k) {
        int e = tid + k * 1024;
        ull x = KY[e];
        if (x != 0ull) {
            int run = e >> 12;               // 0 or 1
            int pos = e & (RUNSZ - 1);
            const ull* other = &KY[run ? 0 : RUNSZ];
            int lo = 0, hi = RUNSZ;
            while (lo < hi) {
                int mid = (lo + hi) >> 1;
                if (other[mid] > x) lo = mid + 1; else hi = mid;
            }
            int rank = pos + lo;             // < cntA <= 8192 < PRE
            uint32_t f = ~(uint32_t)x;
            FI[rank] = f;
            uint32_t q = qclamp(f / NC);
            atomicAdd(&ccnt[(f - (f / NC) * NC) % NC], 1u);
            float4 bb = PBS[q];
            float x1 = (bb.x - 0.5f * bb.z) * iw;
            float y1 = (bb.y - 0.5f * bb.w) * ih;
            float x2 = (bb.x + 0.5f * bb.z) * iw;
            float y2 = (bb.y + 0.5f * bb.w) * ih;
            uint32_t km = fkey(fmaxf(fmaxf(x1, y1), fmaxf(x2, y2)));
            if (km > lmx) lmx = km;
        }
    }
    #pragma unroll
    for (int k = 0; k < 4; ++k) {
        int p = tid + k * 1024;
        int rank = (int)cntA + p;
        if (p < (int)cntB && rank < PRE) {
            ull x = KY[SEGA + p];
            if (x != 0ull) {
                uint32_t f = ~(uint32_t)x;
                FI[rank] = f;
                uint32_t q = qclamp(f / NC);
                atomicAdd(&ccnt[(f - (f / NC) * NC) % NC], 1u);
                float4 bb = PBS[q];
                float x1 = (bb.x - 0.5f * bb.z) * iw;
                float y1 = (bb.y - 0.5f * bb.w) * ih;
                float x2 = (bb.x + 0.5f * bb.z) * iw;
                float y2 = (bb.y + 0.5f * bb.w) * ih;
                uint32_t km = fkey(fmaxf(fmaxf(x1, y1), fmaxf(x2, y2)));
                if (km > lmx) lmx = km;
            }
        }
    }
    for (int off = 32; off > 0; off >>= 1) {
        uint32_t o = (uint32_t)__shfl_down((int)lmx, off, 64);
        if (o > lmx) lmx = o;
    }
    if (lane == 0) smx[tid >> 6] = lmx;
    __syncthreads();
    if (tid == 0) {
        uint32_t m = smx[0];
        for (int wv = 1; wv < 16; ++wv) if (smx[wv] > m) m = smx[wv];
        uint32_t b = (m & 0x80000000u) ? (m & 0x7FFFFFFFu) : ~m;
        sOffD = __uint_as_float(b) + 1.0f;   // max_coord + 1
        uint32_t run = 0;
        for (int c = 0; c < NC; ++c) { cstart[c] = run; cfill[c] = run; run += ccnt[c]; }
        cstart[NC] = run;
    }
    __syncthreads();
    const float offD = sOffD;

    // ---- Phase 5: class-bucket scatter (clist aliases KY; all KY reads done) ----
    #pragma unroll
    for (int k = 0; k < 10; ++k) {
        int r = tid + k * 1024;
        if (r < PRE) {
            uint32_t c = FI[r] % NC;
            uint32_t pos = atomicAdd(&cfill[c], 1u);
            if (pos < PRE) clist[pos] = (unsigned short)r;
        }
    }
    __syncthreads();

    // ---- Phase 6: windowed greedy NMS (16-wide) ----
    int wstart = 0;
    int pick = 0;
    while (pick < POST) {
        while (wstart < WPRE && actw[wstart] == 0u) ++wstart;   // uniform
        if (wstart >= WPRE) {
            uint32_t fi = FI[0];
            uint32_t qi = qclamp(fi / NC);
            uint32_t ci = fi - (fi / NC) * NC;
            float4 bb = PBS[qi];
            float rx1 = (bb.x - 0.5f * bb.z) * iw;
            float ry1 = (bb.y - 0.5f * bb.w) * ih;
            float rx2 = (bb.x + 0.5f * bb.z) * iw;
            float ry2 = (bb.y + 0.5f * bb.w) * ih;
            float score = 1.0f / (1.0f + expf(-lg[(fi < NQC) ? fi : 0]));
            for (int p = pick + tid; p < POST; p += 1024) {
                out[img * POST + p] = score;
                out[BS * POST + img * POST + p] = (float)ci;
                float* ob = out + 2 * BS * POST + ((size_t)img * POST + p) * 4;
                ob[0] = rx1; ob[1] = ry1; ob[2] = rx2; ob[3] = ry2;
            }
            break;
        }

        // wave 0: parallel extraction of first <=16 active indices + candidate boxes
        if (tid < 64) {
            int wI = wstart + tid;
            uint32_t w = (wI < WPRE) ? actw[wI] : 0u;
            int c = __popc(w);
            int inc = c;
            #pragma unroll
            for (int off = 1; off < 64; off <<= 1) {
                int o = __shfl_up(inc, off, 64);
                if (tid >= off) inc += o;
            }
            int pre = inc - c;
            while (w != 0u && pre < K_WIN) {
                int b = __ffs(w) - 1; w &= w - 1u;
                s_cand[pre] = wI * 32 + b;
                ++pre;
            }
            int total = __shfl(inc, 63, 64);
            int nc = (total < K_WIN) ? total : K_WIN;
            if (tid == 0) s_ncand = nc;
            if (tid < nc) {
                int r = s_cand[tid];
                uint32_t fi = FI[r];
                uint32_t q = qclamp(fi / NC);
                int cc = (int)(fi - (fi / NC) * NC);
                float4 bb = PBS[q];
                float x1 = (bb.x - 0.5f * bb.z) * iw;
                float y1 = (bb.y - 0.5f * bb.w) * ih;
                float x2 = (bb.x + 0.5f * bb.z) * iw;
                float y2 = (bb.y + 0.5f * bb.w) * ih;
                float o = (float)cc * offD;
                float a1 = x1 + o, b1 = y1 + o, a2 = x2 + o, b2 = y2 + o;
                s_cx1[tid] = a1; s_cy1[tid] = b1; s_cx2[tid] = a2; s_cy2[tid] = b2;
                s_car[tid] = (a2 - a1) * (b2 - b1);
                s_ccl[tid] = cc;
                s_cbs[tid] = (int)cstart[(cc >= 0 && cc < NC) ? cc : 0];
                s_cbe[tid] = (int)cstart[((cc >= 0 && cc < NC) ? cc : 0) + 1];
            }
        }
        __syncthreads();
        const int ncand = s_ncand;

        // conflict matrix: 256 pairs via 4 ballots
        ull cm[4];
        #pragma unroll
        for (int k = 0; k < 4; ++k) {
            int p = k * 64 + lane;
            int pj = p >> 4, pm = p & 15;
            bool conf = false;
            if (pm < pj && pj < ncand) {
                float xx1 = fmaxf(s_cx1[pm], s_cx1[pj]);
                float yy1 = fmaxf(s_cy1[pm], s_cy1[pj]);
                float xx2 = fminf(s_cx2[pm], s_cx2[pj]);
                float yy2 = fminf(s_cy2[pm], s_cy2[pj]);
                float inter = fmaxf(xx2 - xx1, 0.0f) * fmaxf(yy2 - yy1, 0.0f);
                float uni = (s_car[pm] + s_car[pj]) - inter;
                float iou = inter / fmaxf(uni, 1e-9f);
                conf = !(iou <= 0.7f);
            }
            cm[k] = __ballot(conf);
        }
        uint32_t accMask = 0u;
        int A = 0;
        const int maxA = POST - pick;
        #pragma unroll
        for (int j = 0; j < K_WIN; ++j) {
            uint32_t row = (uint32_t)(cm[j >> 2] >> ((j & 3) * 16)) & 0xFFFFu;
            if (j < ncand && A < maxA && ((row & accMask) == 0u)) { accMask |= (1u << j); ++A; }
        }

        // outputs (pick order = candidate order among accepted)
        #pragma unroll
        for (int j = 0; j < K_WIN; ++j) {
            if ((accMask >> j) & 1u) {
                int ord = __popc(accMask & ((1u << j) - 1u));
                if (tid == ord) {
                    int r = s_cand[j];
                    uint32_t fi = FI[r];
                    uint32_t qi = qclamp(fi / NC);
                    uint32_t ci = fi - (fi / NC) * NC;
                    float4 bb = PBS[qi];
                    float rx1 = (bb.x - 0.5f * bb.z) * iw;
                    float ry1 = (bb.y - 0.5f * bb.w) * ih;
                    float rx2 = (bb.x + 0.5f * bb.z) * iw;
                    float ry2 = (bb.y + 0.5f * bb.w) * ih;
                    float score = 1.0f / (1.0f + expf(-lg[(fi < NQC) ? fi : 0]));
                    int p = pick + ord;
                    out[img * POST + p] = score;
                    out[BS * POST + img * POST + p] = (float)ci;
                    float* ob = out + 2 * BS * POST + ((size_t)img * POST + p) * 4;
                    ob[0] = rx1; ob[1] = ry1; ob[2] = rx2; ob[3] = ry2;
                }
            }
        }

        // flattened suppression over (accepted j, bucket item)
        int startj[K_WIN];
        int tot = 0;
        #pragma unroll
        for (int j = 0; j < K_WIN; ++j) {
            startj[j] = tot;
            if ((accMask >> j) & 1u) tot += s_cbe[j] - s_cbs[j];
        }
        for (int t2 = tid; t2 < tot; t2 += 1024) {
            int j = 0;
            #pragma unroll
            for (int jj = 1; jj < K_WIN; ++jj) if (startj[jj] <= t2) j = jj;
            int r2 = clist[s_cbs[j] + (t2 - startj[j])];
            if (actw[r2 >> 5] & (1u << (r2 & 31))) {
                float o = (float)s_ccl[j] * offD;
                uint32_t f2 = FI[r2];
                uint32_t q2 = qclamp(f2 / NC);
                float4 bb = PBS[q2];
                float jx1 = (bb.x - 0.5f * bb.z) * iw + o;
                float jy1 = (bb.y - 0.5f * bb.w) * ih + o;
                float jx2 = (bb.x + 0.5f * bb.z) * iw + o;
                float jy2 = (bb.y + 0.5f * bb.w) * ih + o;
                float arj = (jx2 - jx1) * (jy2 - jy1);
                float xx1 = fmaxf(s_cx1[j], jx1);
                float yy1 = fmaxf(s_cy1[j], jy1);
                float xx2 = fminf(s_cx2[j], jx2);
                float yy2 = fminf(s_cy2[j], jy2);
                float inter = fmaxf(xx2 - xx1, 0.0f) * fmaxf(yy2 - yy1, 0.0f);
                float uni = (s_car[j] + arj) - inter;
                float iou = inter / fmaxf(uni, 1e-9f);
                if (!(iou <= 0.7f)) atomicAnd(&actw[r2 >> 5], ~(1u << (r2 & 31)));
            }
        }
        pick += A;
        __syncthreads();
    }
}

extern "C" void kernel_launch(void* const* d_in, const int* in_sizes, int n_in,
                              void* d_out, int out_size, void* d_ws, size_t ws_size,
                              hipStream_t stream) {
    const float* logits = (const float*)d_in[0];
    const float* boxes  = (const float*)d_in[1];
    const float* tsizes = (const float*)d_in[2];
    float* out = (float*)d_out;

    k_fused<<<BS, 1024, 0, stream>>>(logits, boxes, tsizes, out);
}

// Round 11
// 258.193 us; speedup vs baseline: 1.1887x; 1.1887x over previous
//
#include <hip/hip_runtime.h>
#include <cstdint>

#pragma clang fp contract(off)

#define BS   128
#define NQ   900
#define NC   91
#define NQC  (NQ * NC)   // 81900
#define Q4   (NQC / 4)   // 20475
#define PRE  10000
#define POST 100
#define SEGA 8192
#define SEGB 4096
#define RUNSZ 4096
#define RUNS 3
#define KSTRIDE (RUNS * RUNSZ)    // 12288 keys per image
#define CNTS 16
#define TBITS 13
#define TBINS (1 << TBITS)
#define TSHIFT (32 - TBITS)
#define WPRE 320                  // ceil(PRE/32) words for active bitmask
#define K_WIN 16

typedef unsigned long long ull;

// ---- workspace layout (bytes); zeroing done in k_select ----
#define WS_CNT    0            // 128*CNTS*4 = 8 KB
#define WS_THR    8192         // 128*2*4 = 1 KB
#define WS_KEYS   16384        // 128*12288*8 = 12.6 MB

__device__ __forceinline__ uint32_t fkey(float f) {
    uint32_t b = __float_as_uint(f);
    return (b & 0x80000000u) ? ~b : (b | 0x80000000u);
}
// defensive clamp: valid keys give q < NQ; turns capacity bugs into wrong-value not fault
__device__ __forceinline__ uint32_t qclamp(uint32_t q) { return (q < NQ) ? q : (NQ - 1); }

// ============ Kernel 1: per-image LDS histogram -> thresholds; zero counters ============
// (R8 version — fused hist+thresh; R9's split into two kernels cost ~+18 us net.)
// T_lo: largest bin boundary with suffix >= PRE; T_hi: smallest with suffix <= SEGA.
// Segment A: key >= T_hi (<= 8192). Segment B: [T_lo, T_hi) (~1940 typ, <= 4096;
// rare 8-bit refine if the straddling bin is fat). A-keys all > B-keys.
__global__ void __launch_bounds__(1024) k_select(const float* __restrict__ logits,
                                                 uint32_t* __restrict__ cnt,
                                                 uint32_t* __restrict__ thr) {
    int img = blockIdx.x;
    const int tid = threadIdx.x;
    __shared__ uint32_t hist[TBINS];   // 32 KB
    __shared__ uint32_t part[1024];
    __shared__ uint32_t part2[32];
    __shared__ uint32_t sTlo, sThi, sBlo, sCumAboveLo, sM, sM1;
    for (int i = tid; i < TBINS; i += 1024) hist[i] = 0u;
    if (tid == 0) { cnt[img * CNTS + 0] = 0u; cnt[img * CNTS + 1] = 0u; }
    __syncthreads();
    const float4* lg4 = (const float4*)(logits + (size_t)img * NQC);
    for (int i = tid; i < Q4; i += 1024) {
        float4 v = lg4[i];
        atomicAdd(&hist[fkey(v.x) >> TSHIFT], 1u);
        atomicAdd(&hist[fkey(v.y) >> TSHIFT], 1u);
        atomicAdd(&hist[fkey(v.z) >> TSHIFT], 1u);
        atomicAdd(&hist[fkey(v.w) >> TSHIFT], 1u);
    }
    __syncthreads();
    {
        uint32_t s = 0;
        int base = tid * (TBINS / 1024);
        for (int j = 0; j < TBINS / 1024; ++j) s += hist[base + j];
        part[tid] = s;
    }
    __syncthreads();
    if (tid < 32) {
        uint32_t s2 = 0;
        for (int j = 0; j < 32; ++j) s2 += part[tid * 32 + j];
        part2[tid] = s2;
    }
    __syncthreads();
    if (tid == 0) {
        uint32_t cum = 0; int w = 31;
        for (; w > 0; --w) { if (cum + part2[w] >= PRE) break; cum += part2[w]; }
        int t = w * 32 + 31;
        for (; t > w * 32; --t) { if (cum + part[t] >= PRE) break; cum += part[t]; }
        int b = t * (TBINS / 1024) + (TBINS / 1024 - 1);
        for (; b > t * (TBINS / 1024); --b) { if (cum + hist[b] >= PRE) break; cum += hist[b]; }
        sBlo = (uint32_t)b;
        sCumAboveLo = cum;
        sM = cum + hist[b];
        sTlo = ((uint32_t)b) << TSHIFT;
        uint32_t cum2 = 0; int w2 = 31;
        for (; w2 >= 0; --w2) { if (cum2 + part2[w2] > SEGA) break; cum2 += part2[w2]; }
        int t2 = w2 * 32 + 31;
        for (; t2 >= w2 * 32; --t2) { if (cum2 + part[t2] > SEGA) break; cum2 += part[t2]; }
        int b2 = t2 * (TBINS / 1024) + (TBINS / 1024 - 1);
        for (; b2 >= t2 * (TBINS / 1024); --b2) { if (cum2 + hist[b2] > SEGA) break; cum2 += hist[b2]; }
        sM1 = cum2;
        sThi = (b2 >= TBINS - 1) ? 0xFFFFFFFFu : (((uint32_t)(b2 + 1)) << TSHIFT);
    }
    __syncthreads();
    if (sM - sM1 > SEGB) {   // block-uniform rare fallback: refine Tlo by 8 bits
        uint32_t P = sBlo;
        for (int i = tid; i < 256; i += 1024) part[i] = 0u;
        __syncthreads();
        for (int i = tid; i < Q4; i += 1024) {
            float4 v = lg4[i];
            uint32_t u;
            u = fkey(v.x); if ((u >> TSHIFT) == P) atomicAdd(&part[(u >> (TSHIFT - 8)) & 0xFFu], 1u);
            u = fkey(v.y); if ((u >> TSHIFT) == P) atomicAdd(&part[(u >> (TSHIFT - 8)) & 0xFFu], 1u);
            u = fkey(v.z); if ((u >> TSHIFT) == P) atomicAdd(&part[(u >> (TSHIFT - 8)) & 0xFFu], 1u);
            u = fkey(v.w); if ((u >> TSHIFT) == P) atomicAdd(&part[(u >> (TSHIFT - 8)) & 0xFFu], 1u);
        }
        __syncthreads();
        if (tid == 0) {
            uint32_t K = PRE - sCumAboveLo;
            uint32_t cum = 0; int x = 255;
            for (; x > 0; --x) { if (cum + part[x] >= K) break; cum += part[x]; }
            sTlo = (P << TSHIFT) | (((uint32_t)x) << (TSHIFT - 8));
        }
        __syncthreads();
    }
    if (tid == 0) { thr[img * 2 + 0] = sTlo; thr[img * 2 + 1] = sThi; }
}

// ============ Kernel 2: two-way compaction, 20 blocks/image, block-aggregated atomics ============
__global__ void __launch_bounds__(1024) k_compact(const float* __restrict__ logits,
                                                  const uint32_t* __restrict__ thr,
                                                  uint32_t* __restrict__ cnt,
                                                  ull* __restrict__ keys) {
    int img = blockIdx.y;
    const int tid = threadIdx.x;
    const int lane = tid & 63;
    __shared__ uint32_t sA, sB, gA, gB;
    if (tid == 0) { sA = 0u; sB = 0u; }
    __syncthreads();
    const uint32_t Tlo = thr[img * 2 + 0], Thi = thr[img * 2 + 1];
    const float* lg = logits + (size_t)img * NQC;
    const int base = blockIdx.x * 4096 + tid;

    uint32_t ukey[4]; bool fa[4], fb[4];
    uint32_t belowA[4], belowB[4], tAr[4], tBr[4];
    uint32_t TA = 0u, TB = 0u;
    #pragma unroll
    for (int r = 0; r < 4; ++r) {
        int i = base + r * 1024;
        uint32_t u = 0u; bool a = false, b = false;
        if (i < NQC) {
            u = fkey(lg[i]);
            a = (u >= Thi);
            b = !a && (u >= Tlo);
        }
        ukey[r] = u; fa[r] = a; fb[r] = b;
        ull ma = __ballot(a), mb = __ballot(b);
        belowA[r] = (uint32_t)__popcll(ma & ((1ull << lane) - 1ull));
        belowB[r] = (uint32_t)__popcll(mb & ((1ull << lane) - 1ull));
        tAr[r] = (uint32_t)__popcll(ma);
        tBr[r] = (uint32_t)__popcll(mb);
        TA += tAr[r]; TB += tBr[r];
    }
    uint32_t wbA = 0u, wbB = 0u;
    if (lane == 0) {
        if (TA) wbA = atomicAdd(&sA, TA);
        if (TB) wbB = atomicAdd(&sB, TB);
    }
    wbA = __shfl(wbA, 0, 64);
    wbB = __shfl(wbB, 0, 64);
    __syncthreads();
    if (tid == 0) {
        gA = sA ? atomicAdd(&cnt[img * CNTS + 0], sA) : 0u;
        gB = sB ? atomicAdd(&cnt[img * CNTS + 1], sB) : 0u;
    }
    __syncthreads();
    ull* kI = keys + (size_t)img * KSTRIDE;
    uint32_t preA = 0u, preB = 0u;
    #pragma unroll
    for (int r = 0; r < 4; ++r) {
        int i = base + r * 1024;
        ull kv = ((ull)ukey[r] << 32) | (ull)(0xFFFFFFFFu - (uint32_t)i);
        if (fa[r]) { uint32_t p = gA + wbA + preA + belowA[r]; if (p < SEGA) kI[p] = kv; }
        if (fb[r]) { uint32_t p = gB + wbB + preB + belowB[r]; if (p < SEGB) kI[SEGA + p] = kv; }
        preA += tAr[r]; preB += tBr[r];
    }
}

// ============ Kernel 3: bitonic sort of 3 runs of 4096 (desc), zero-padded, 384 blocks ============
__global__ void __launch_bounds__(1024) k_sortrun(ull* __restrict__ keys,
                                                  const uint32_t* __restrict__ cnt) {
    int img = blockIdx.y;
    int run = blockIdx.x;
    const int tid = threadIdx.x;
    uint32_t cntA = cnt[img * CNTS + 0]; if (cntA > SEGA) cntA = SEGA;
    uint32_t cntB = cnt[img * CNTS + 1]; if (cntB > SEGB) cntB = SEGB;
    int n = (run == 0) ? ((cntA < RUNSZ) ? (int)cntA : RUNSZ)
          : (run == 1) ? ((cntA > RUNSZ) ? (int)(cntA - RUNSZ) : 0)
                       : (int)cntB;
    ull* base = keys + (size_t)img * KSTRIDE + (size_t)run * RUNSZ;
    __shared__ ull sh[RUNSZ];   // 32 KB
    for (int i = tid; i < RUNSZ; i += 1024) sh[i] = (i < n) ? base[i] : 0ull;
    __syncthreads();
    for (int k = 2; k <= RUNSZ; k <<= 1) {
        for (int j = k >> 1; j > 0; j >>= 1) {
            for (int t = tid; t < RUNSZ / 2; t += 1024) {
                int i = ((t & ~(j - 1)) << 1) | (t & (j - 1));
                int ixj = i | j;
                ull a = sh[i], b = sh[ixj];
                bool sw = ((i & k) == 0) ? (a < b) : (a > b);
                if (sw) { sh[i] = b; sh[ixj] = a; }
            }
            __syncthreads();
        }
    }
    for (int i = tid; i < RUNSZ; i += 1024) base[i] = sh[i];
}

// ============ Kernel 4: LDS rank-merge + windowed greedy NMS (R9 version, 88 us) ============
// Runs 0,1 (segment A) merged by LDS binary search; segment B concats below A.
// Cross-class suppression provably impossible (offset bands: inter <= area/4 => IoU <= 1/3
// < 0.7): suppression scans only accepted candidates' class buckets. 16-candidate windows:
// extraction wave-parallel (prefix-scan over 64 actw words), conflict matrix via 4 ballots.
__global__ void __launch_bounds__(1024) k_nms(const ull* __restrict__ keys,
                                              const uint32_t* __restrict__ cnt,
                                              const float* __restrict__ logits,
                                              const float* __restrict__ pred_boxes,
                                              const float* __restrict__ target_sizes,
                                              float* __restrict__ out) {
    int img = blockIdx.x;
    const int tid = threadIdx.x;
    const int lane = tid & 63;
    __shared__ ull shA[SEGA];               // 64 KB: runs 0+1 (sorted desc, zero-padded)
    __shared__ float4 shPB[NQ];             // 14.4 KB: pred_boxes
    __shared__ uint32_t fidx[PRE];          // 40000 B
    __shared__ unsigned short clist[PRE];   // 20000 B
    __shared__ uint32_t actw[WPRE];
    __shared__ uint32_t ccnt[NC];
    __shared__ uint32_t cstart[NC + 1];
    __shared__ uint32_t cfill[NC];
    __shared__ uint32_t smx[16];
    __shared__ float sOffD;
    __shared__ int   s_ncand;
    __shared__ int   s_cand[K_WIN];
    __shared__ float s_cx1[K_WIN], s_cy1[K_WIN], s_cx2[K_WIN], s_cy2[K_WIN], s_car[K_WIN];
    __shared__ int   s_ccl[K_WIN], s_cbs[K_WIN], s_cbe[K_WIN];

    const float ih = target_sizes[img * 2 + 0];
    const float iw = target_sizes[img * 2 + 1];
    const float* pb = pred_boxes + (size_t)img * NQ * 4;
    const float* lg = logits + (size_t)img * NQC;
    const ull* kI = keys + (size_t)img * KSTRIDE;
    uint32_t cntA = cnt[img * CNTS + 0]; if (cntA > SEGA) cntA = SEGA;
    uint32_t cntB = cnt[img * CNTS + 1]; if (cntB > SEGB) cntB = SEGB;

    // Phase 0: load A runs + pred_boxes into LDS; init masks/counters
    #pragma unroll
    for (int k = 0; k < 8; ++k) shA[tid + k * 1024] = kI[tid + k * 1024];
    if (tid < NQ) shPB[tid] = ((const float4*)pb)[tid];
    for (int c = tid; c < NC; c += 1024) ccnt[c] = 0u;
    for (int wI = tid; wI < WPRE; wI += 1024) {
        int base = wI * 32;
        uint32_t m = 0xFFFFFFFFu;
        if (base + 32 > PRE) m = (base >= PRE) ? 0u : (0xFFFFFFFFu >> (base + 32 - PRE));
        actw[wI] = m;
    }
    __syncthreads();

    // Phase 1: rank A (binary search in LDS), concat B; fidx scatter, class hist, max coord
    uint32_t lmx = 0u;
    #pragma unroll
    for (int k = 0; k < 8; ++k) {
        int e = tid + k * 1024;
        ull x = shA[e];
        if (x != 0ull) {
            int run = e >> 12;
            int pos = e & (RUNSZ - 1);
            const ull* other = &shA[run ? 0 : RUNSZ];
            int lo = 0, hi = RUNSZ;
            while (lo < hi) {
                int mid = (lo + hi) >> 1;
                if (other[mid] > x) lo = mid + 1; else hi = mid;
            }
            int rank = pos + lo;
            uint32_t f = ~(uint32_t)x;
            fidx[rank] = f;
            uint32_t q = qclamp(f / NC);
            atomicAdd(&ccnt[(f - (f / NC) * NC) % NC], 1u);
            float4 bb = shPB[q];
            float x1 = (bb.x - 0.5f * bb.z) * iw;
            float y1 = (bb.y - 0.5f * bb.w) * ih;
            float x2 = (bb.x + 0.5f * bb.z) * iw;
            float y2 = (bb.y + 0.5f * bb.w) * ih;
            uint32_t km = fkey(fmaxf(fmaxf(x1, y1), fmaxf(x2, y2)));
            if (km > lmx) lmx = km;
        }
    }
    #pragma unroll
    for (int k = 0; k < 4; ++k) {
        int p = tid + k * 1024;
        int rank = (int)cntA + p;
        if (p < (int)cntB && rank < PRE) {
            ull x = kI[SEGA + p];
            if (x != 0ull) {
                uint32_t f = ~(uint32_t)x;
                fidx[rank] = f;
                uint32_t q = qclamp(f / NC);
                atomicAdd(&ccnt[(f - (f / NC) * NC) % NC], 1u);
                float4 bb = shPB[q];
                float x1 = (bb.x - 0.5f * bb.z) * iw;
                float y1 = (bb.y - 0.5f * bb.w) * ih;
                float x2 = (bb.x + 0.5f * bb.z) * iw;
                float y2 = (bb.y + 0.5f * bb.w) * ih;
                uint32_t km = fkey(fmaxf(fmaxf(x1, y1), fmaxf(x2, y2)));
                if (km > lmx) lmx = km;
            }
        }
    }
    for (int off = 32; off > 0; off >>= 1) {
        uint32_t o = (uint32_t)__shfl_down((int)lmx, off, 64);
        if (o > lmx) lmx = o;
    }
    if (lane == 0) smx[tid >> 6] = lmx;
    __syncthreads();
    if (tid == 0) {
        uint32_t m = smx[0];
        for (int wv = 1; wv < 16; ++wv) if (smx[wv] > m) m = smx[wv];
        uint32_t b = (m & 0x80000000u) ? (m & 0x7FFFFFFFu) : ~m;
        sOffD = __uint_as_float(b) + 1.0f;   // max_coord + 1
        uint32_t run = 0;
        for (int c = 0; c < NC; ++c) { cstart[c] = run; cfill[c] = run; run += ccnt[c]; }
        cstart[NC] = run;
    }
    __syncthreads();
    const float offD = sOffD;

    // Phase 2: class-bucket scatter
    #pragma unroll
    for (int k = 0; k < 10; ++k) {
        int r = tid + k * 1024;
        if (r < PRE) {
            uint32_t c = fidx[r] % NC;
            uint32_t pos = atomicAdd(&cfill[c], 1u);
            if (pos < PRE) clist[pos] = (unsigned short)r;
        }
    }
    __syncthreads();

    // Phase 3: windowed greedy picks (16-wide)
    int wstart = 0;
    int pick = 0;
    while (pick < POST) {
        while (wstart < WPRE && actw[wstart] == 0u) ++wstart;   // uniform
        if (wstart >= WPRE) {
            uint32_t fi = fidx[0];
            uint32_t qi = qclamp(fi / NC);
            uint32_t ci = fi - (fi / NC) * NC;
            float4 bb = shPB[qi];
            float rx1 = (bb.x - 0.5f * bb.z) * iw;
            float ry1 = (bb.y - 0.5f * bb.w) * ih;
            float rx2 = (bb.x + 0.5f * bb.z) * iw;
            float ry2 = (bb.y + 0.5f * bb.w) * ih;
            float score = 1.0f / (1.0f + expf(-lg[(fi < NQC) ? fi : 0]));
            for (int p = pick + tid; p < POST; p += 1024) {
                out[img * POST + p] = score;
                out[BS * POST + img * POST + p] = (float)ci;
                float* ob = out + 2 * BS * POST + ((size_t)img * POST + p) * 4;
                ob[0] = rx1; ob[1] = ry1; ob[2] = rx2; ob[3] = ry2;
            }
            break;
        }

        // wave 0: parallel extraction of first <=16 active indices + candidate boxes
        if (tid < 64) {
            int wI = wstart + tid;
            uint32_t w = (wI < WPRE) ? actw[wI] : 0u;
            int c = __popc(w);
            int inc = c;
            #pragma unroll
            for (int off = 1; off < 64; off <<= 1) {
                int o = __shfl_up(inc, off, 64);
                if (tid >= off) inc += o;
            }
            int pre = inc - c;
            while (w != 0u && pre < K_WIN) {
                int b = __ffs(w) - 1; w &= w - 1u;
                s_cand[pre] = wI * 32 + b;
                ++pre;
            }
            int total = __shfl(inc, 63, 64);
            int nc = (total < K_WIN) ? total : K_WIN;
            if (tid == 0) s_ncand = nc;
            if (tid < nc) {
                int r = s_cand[tid];
                uint32_t fi = fidx[r];
                uint32_t q = qclamp(fi / NC);
                int cc = (int)(fi - (fi / NC) * NC);
                float4 bb = shPB[q];
                float x1 = (bb.x - 0.5f * bb.z) * iw;
                float y1 = (bb.y - 0.5f * bb.w) * ih;
                float x2 = (bb.x + 0.5f * bb.z) * iw;
                float y2 = (bb.y + 0.5f * bb.w) * ih;
                float o = (float)cc * offD;
                float a1 = x1 + o, b1 = y1 + o, a2 = x2 + o, b2 = y2 + o;
                s_cx1[tid] = a1; s_cy1[tid] = b1; s_cx2[tid] = a2; s_cy2[tid] = b2;
                s_car[tid] = (a2 - a1) * (b2 - b1);
                s_ccl[tid] = cc;
                s_cbs[tid] = (int)cstart[(cc >= 0 && cc < NC) ? cc : 0];
                s_cbe[tid] = (int)cstart[((cc >= 0 && cc < NC) ? cc : 0) + 1];
            }
        }
        __syncthreads();
        const int ncand = s_ncand;

        // conflict matrix: 256 pairs via 4 ballots
        ull cm[4];
        #pragma unroll
        for (int k = 0; k < 4; ++k) {
            int p = k * 64 + lane;
            int pj = p >> 4, pm = p & 15;
            bool conf = false;
            if (pm < pj && pj < ncand) {
                float xx1 = fmaxf(s_cx1[pm], s_cx1[pj]);
                float yy1 = fmaxf(s_cy1[pm], s_cy1[pj]);
                float xx2 = fminf(s_cx2[pm], s_cx2[pj]);
                float yy2 = fminf(s_cy2[pm], s_cy2[pj]);
                float inter = fmaxf(xx2 - xx1, 0.0f) * fmaxf(yy2 - yy1, 0.0f);
                float uni = (s_car[pm] + s_car[pj]) - inter;
                float iou = inter / fmaxf(uni, 1e-9f);
                conf = !(iou <= 0.7f);
            }
            cm[k] = __ballot(conf);
        }
        uint32_t accMask = 0u;
        int A = 0;
        const int maxA = POST - pick;
        #pragma unroll
        for (int j = 0; j < K_WIN; ++j) {
            uint32_t row = (uint32_t)(cm[j >> 2] >> ((j & 3) * 16)) & 0xFFFFu;
            if (j < ncand && A < maxA && ((row & accMask) == 0u)) { accMask |= (1u << j); ++A; }
        }

        // outputs (pick order = candidate order among accepted)
        #pragma unroll
        for (int j = 0; j < K_WIN; ++j) {
            if ((accMask >> j) & 1u) {
                int ord = __popc(accMask & ((1u << j) - 1u));
                if (tid == ord) {
                    int r = s_cand[j];
                    uint32_t fi = fidx[r];
                    uint32_t qi = qclamp(fi / NC);
                    uint32_t ci = fi - (fi / NC) * NC;
                    float4 bb = shPB[qi];
                    float rx1 = (bb.x - 0.5f * bb.z) * iw;
                    float ry1 = (bb.y - 0.5f * bb.w) * ih;
                    float rx2 = (bb.x + 0.5f * bb.z) * iw;
                    float ry2 = (bb.y + 0.5f * bb.w) * ih;
                    float score = 1.0f / (1.0f + expf(-lg[(fi < NQC) ? fi : 0]));
                    int p = pick + ord;
                    out[img * POST + p] = score;
                    out[BS * POST + img * POST + p] = (float)ci;
                    float* ob = out + 2 * BS * POST + ((size_t)img * POST + p) * 4;
                    ob[0] = rx1; ob[1] = ry1; ob[2] = rx2; ob[3] = ry2;
                }
            }
        }

        // flattened suppression over (accepted j, bucket item)
        int startj[K_WIN];
        int tot = 0;
        #pragma unroll
        for (int j = 0; j < K_WIN; ++j) {
            startj[j] = tot;
            if ((accMask >> j) & 1u) tot += s_cbe[j] - s_cbs[j];
        }
        for (int t2 = tid; t2 < tot; t2 += 1024) {
            int j = 0;
            #pragma unroll
            for (int jj = 1; jj < K_WIN; ++jj) if (startj[jj] <= t2) j = jj;
            int r2 = clist[s_cbs[j] + (t2 - startj[j])];
            if (actw[r2 >> 5] & (1u << (r2 & 31))) {
                float o = (float)s_ccl[j] * offD;
                uint32_t f2 = fidx[r2];
                uint32_t q2 = qclamp(f2 / NC);
                float4 bb = shPB[q2];
                float jx1 = (bb.x - 0.5f * bb.z) * iw + o;
                float jy1 = (bb.y - 0.5f * bb.w) * ih + o;
                float jx2 = (bb.x + 0.5f * bb.z) * iw + o;
                float jy2 = (bb.y + 0.5f * bb.w) * ih + o;
                float arj = (jx2 - jx1) * (jy2 - jy1);
                float xx1 = fmaxf(s_cx1[j], jx1);
                float yy1 = fmaxf(s_cy1[j], jy1);
                float xx2 = fminf(s_cx2[j], jx2);
                float yy2 = fminf(s_cy2[j], jy2);
                float inter = fmaxf(xx2 - xx1, 0.0f) * fmaxf(yy2 - yy1, 0.0f);
                float uni = (s_car[j] + arj) - inter;
                float iou = inter / fmaxf(uni, 1e-9f);
                if (!(iou <= 0.7f)) atomicAnd(&actw[r2 >> 5], ~(1u << (r2 & 31)));
            }
        }
        pick += A;
        __syncthreads();
    }
}

extern "C" void kernel_launch(void* const* d_in, const int* in_sizes, int n_in,
                              void* d_out, int out_size, void* d_ws, size_t ws_size,
                              hipStream_t stream) {
    const float* logits = (const float*)d_in[0];
    const float* boxes  = (const float*)d_in[1];
    const float* tsizes = (const float*)d_in[2];
    float* out = (float*)d_out;

    char* ws = (char*)d_ws;
    uint32_t* cnt = (uint32_t*)(ws + WS_CNT);
    uint32_t* thr = (uint32_t*)(ws + WS_THR);
    ull* keys = (ull*)(ws + WS_KEYS);

    k_select<<<BS, 1024, 0, stream>>>(logits, cnt, thr);
    k_compact<<<dim3(20, BS), 1024, 0, stream>>>(logits, thr, cnt, keys);
    k_sortrun<<<dim3(RUNS, BS), 1024, 0, stream>>>(keys, cnt);
    k_nms<<<BS, 1024, 0, stream>>>(keys, cnt, logits, boxes, tsizes, out);
}

// Round 12
// 249.248 us; speedup vs baseline: 1.2314x; 1.0359x over previous
//
#include <hip/hip_runtime.h>
#include <cstdint>

#pragma clang fp contract(off)

#define BS   128
#define NQ   900
#define NC   91
#define NQC  (NQ * NC)   // 81900
#define Q4   (NQC / 4)   // 20475
#define THIRD (NQC / 3)  // 27300
#define T4   (THIRD / 4) // 6825
#define PRE  10000
#define POST 100
#define RUNSZ 4096
#define RUNS 3
#define KSTRIDE (RUNS * RUNSZ)    // 12288 keys per image
#define TBITS 13
#define TBINS (1 << TBITS)
#define TSHIFT (32 - TBITS)
#define WPRE 320                  // ceil(PRE/32) words for active bitmask
#define K_WIN 16
#define M_CAP 11000               // refine threshold: keeps per-run count >=6 sigma below 4096

typedef unsigned long long ull;

// ---- workspace layout (bytes) ----
#define WS_THR    0            // 128*4
#define WS_KEYS   8192         // 128*12288*8 = 12.6 MB

__device__ __forceinline__ uint32_t fkey(float f) {
    uint32_t b = __float_as_uint(f);
    return (b & 0x80000000u) ? ~b : (b | 0x80000000u);
}
// defensive: valid keys give q < NQ; turns capacity bugs into wrong-value not fault
__device__ __forceinline__ uint32_t qclamp(uint32_t q) { return (q < NQ) ? q : (NQ - 1); }

// ============ Kernel 1: per-image LDS histogram -> single threshold T_lo ============
// T_lo: largest 13-bit bin boundary with suffix-count >= PRE  (M = count(key>=T_lo) in
// [PRE, ~PRE+binwidth]). If M > M_CAP (fat straddling bin), refine T_lo by 8 more bits
// so M stays well under 3*RUNSZ and each index-space third holds <= RUNSZ w.o.p.
__global__ void __launch_bounds__(1024) k_select(const float* __restrict__ logits,
                                                 uint32_t* __restrict__ thr) {
    int img = blockIdx.x;
    const int tid = threadIdx.x;
    __shared__ uint32_t hist[TBINS];   // 32 KB
    __shared__ uint32_t part[1024];
    __shared__ uint32_t part2[32];
    __shared__ uint32_t sTlo, sBlo, sCumAboveLo, sM;
    for (int i = tid; i < TBINS; i += 1024) hist[i] = 0u;
    __syncthreads();
    const float4* lg4 = (const float4*)(logits + (size_t)img * NQC);
    for (int i = tid; i < Q4; i += 1024) {
        float4 v = lg4[i];
        atomicAdd(&hist[fkey(v.x) >> TSHIFT], 1u);
        atomicAdd(&hist[fkey(v.y) >> TSHIFT], 1u);
        atomicAdd(&hist[fkey(v.z) >> TSHIFT], 1u);
        atomicAdd(&hist[fkey(v.w) >> TSHIFT], 1u);
    }
    __syncthreads();
    {
        uint32_t s = 0;
        int base = tid * (TBINS / 1024);
        for (int j = 0; j < TBINS / 1024; ++j) s += hist[base + j];
        part[tid] = s;
    }
    __syncthreads();
    if (tid < 32) {
        uint32_t s2 = 0;
        for (int j = 0; j < 32; ++j) s2 += part[tid * 32 + j];
        part2[tid] = s2;
    }
    __syncthreads();
    if (tid == 0) {
        uint32_t cum = 0; int w = 31;
        for (; w > 0; --w) { if (cum + part2[w] >= PRE) break; cum += part2[w]; }
        int t = w * 32 + 31;
        for (; t > w * 32; --t) { if (cum + part[t] >= PRE) break; cum += part[t]; }
        int b = t * (TBINS / 1024) + (TBINS / 1024 - 1);
        for (; b > t * (TBINS / 1024); --b) { if (cum + hist[b] >= PRE) break; cum += hist[b]; }
        sBlo = (uint32_t)b;
        sCumAboveLo = cum;
        sM = cum + hist[b];
        sTlo = ((uint32_t)b) << TSHIFT;
    }
    __syncthreads();
    if (sM > M_CAP) {   // block-uniform rare fallback: refine Tlo by 8 bits
        uint32_t P = sBlo;
        for (int i = tid; i < 256; i += 1024) part[i] = 0u;
        __syncthreads();
        for (int i = tid; i < Q4; i += 1024) {
            float4 v = lg4[i];
            uint32_t u;
            u = fkey(v.x); if ((u >> TSHIFT) == P) atomicAdd(&part[(u >> (TSHIFT - 8)) & 0xFFu], 1u);
            u = fkey(v.y); if ((u >> TSHIFT) == P) atomicAdd(&part[(u >> (TSHIFT - 8)) & 0xFFu], 1u);
            u = fkey(v.z); if ((u >> TSHIFT) == P) atomicAdd(&part[(u >> (TSHIFT - 8)) & 0xFFu], 1u);
            u = fkey(v.w); if ((u >> TSHIFT) == P) atomicAdd(&part[(u >> (TSHIFT - 8)) & 0xFFu], 1u);
        }
        __syncthreads();
        if (tid == 0) {
            uint32_t K = PRE - sCumAboveLo;
            uint32_t cum = 0; int x = 255;
            for (; x > 0; --x) { if (cum + part[x] >= K) break; cum += part[x]; }
            sTlo = (P << TSHIFT) | (((uint32_t)x) << (TSHIFT - 8));
        }
        __syncthreads();
    }
    if (tid == 0) thr[img] = sTlo;
}

// ============ Kernel 2: fused compact+sort; block (run,img) owns a fixed index third ============
// Scans its 27300 logits vs T_lo, ballot-compacts into LDS (order within a run is
// irrelevant — the 3-way rank merge in k_nms handles any partition), zero-pads, bitonic
// sorts 4096 desc, writes the run. No global counters, no separate compact kernel.
__global__ void __launch_bounds__(1024) k_sortcompact(const float* __restrict__ logits,
                                                      const uint32_t* __restrict__ thr,
                                                      ull* __restrict__ keys) {
    int img = blockIdx.y;
    int run = blockIdx.x;
    const int tid = threadIdx.x;
    const int lane = tid & 63;
    __shared__ ull sh[RUNSZ];   // 32 KB
    __shared__ uint32_t sCnt;
    if (tid == 0) sCnt = 0u;
    __syncthreads();
    const uint32_t Tlo = thr[img];
    const float4* lg4 = (const float4*)(logits + (size_t)img * NQC) + (size_t)run * T4;
    const int fbase = run * THIRD;
    for (int i0 = 0; i0 < T4; i0 += 1024) {
        int i = i0 + tid;
        bool inb = (i < T4);
        float4 v = inb ? lg4[i] : make_float4(0.f, 0.f, 0.f, 0.f);
        float comp[4] = {v.x, v.y, v.z, v.w};
        #pragma unroll
        for (int c = 0; c < 4; ++c) {
            uint32_t u = inb ? fkey(comp[c]) : 0u;
            bool pass = inb && (u >= Tlo);
            ull m = __ballot(pass);
            uint32_t below = (uint32_t)__popcll(m & ((1ull << lane) - 1ull));
            uint32_t wtot = (uint32_t)__popcll(m);
            uint32_t wb = 0u;
            if (lane == 0 && wtot) wb = atomicAdd(&sCnt, wtot);
            wb = __shfl(wb, 0, 64);
            if (pass) {
                uint32_t p = wb + below;
                uint32_t fi = (uint32_t)(fbase + i * 4 + c);
                if (p < RUNSZ) sh[p] = ((ull)u << 32) | (ull)(0xFFFFFFFFu - fi);
            }
        }
    }
    __syncthreads();
    uint32_t n = sCnt; if (n > RUNSZ) n = RUNSZ;
    for (int i = tid; i < RUNSZ; i += 1024) if (i >= (int)n) sh[i] = 0ull;
    __syncthreads();
    for (int k = 2; k <= RUNSZ; k <<= 1) {
        for (int j = k >> 1; j > 0; j >>= 1) {
            for (int t = tid; t < RUNSZ / 2; t += 1024) {
                int i = ((t & ~(j - 1)) << 1) | (t & (j - 1));
                int ixj = i | j;
                ull a = sh[i], b = sh[ixj];
                bool sw = ((i & k) == 0) ? (a < b) : (a > b);
                if (sw) { sh[i] = b; sh[ixj] = a; }
            }
            __syncthreads();
        }
    }
    ull* base = keys + (size_t)img * KSTRIDE + (size_t)run * RUNSZ;
    for (int i = tid; i < RUNSZ; i += 1024) base[i] = sh[i];
}

// ============ Kernel 3: 3-way LDS rank-merge + windowed greedy NMS ============
// All 3 runs in LDS; element rank = pos + count(greater) in the other two runs (exact,
// keys unique via index low bits). rank<PRE -> exact sorted top-PRE in fidx. Cross-class
// suppression provably impossible (offset bands: inter <= area/4 => IoU <= 1/3 < 0.7):
// suppression scans only accepted candidates' class buckets. 16-candidate windows:
// wave-parallel extraction + ballot conflict matrix. clist aliases dead key LDS.
__global__ void __launch_bounds__(1024) k_nms(const ull* __restrict__ keys,
                                              const float* __restrict__ logits,
                                              const float* __restrict__ pred_boxes,
                                              const float* __restrict__ target_sizes,
                                              float* __restrict__ out) {
    int img = blockIdx.x;
    const int tid = threadIdx.x;
    const int lane = tid & 63;
    __shared__ __align__(16) unsigned char smemA[KSTRIDE * 8];   // 96 KB: 3 runs
    __shared__ float4 shPB[NQ];             // 14.4 KB
    __shared__ uint32_t fidx[PRE];          // 40000 B
    __shared__ uint32_t actw[WPRE];
    __shared__ uint32_t ccnt[NC];
    __shared__ uint32_t cstart[NC + 1];
    __shared__ uint32_t cfill[NC];
    __shared__ uint32_t smx[16];
    __shared__ float sOffD;
    __shared__ int   s_ncand;
    __shared__ int   s_cand[K_WIN];
    __shared__ float s_cx1[K_WIN], s_cy1[K_WIN], s_cx2[K_WIN], s_cy2[K_WIN], s_car[K_WIN];
    __shared__ int   s_ccl[K_WIN], s_cbs[K_WIN], s_cbe[K_WIN];

    ull* shA = (ull*)smemA;
    unsigned short* clist = (unsigned short*)smemA;   // aliases shA after phase 1

    const float ih = target_sizes[img * 2 + 0];
    const float iw = target_sizes[img * 2 + 1];
    const float* pb = pred_boxes + (size_t)img * NQ * 4;
    const float* lg = logits + (size_t)img * NQC;
    const ull* kI = keys + (size_t)img * KSTRIDE;

    // Phase 0: load 3 runs + pred_boxes into LDS; init masks/counters
    #pragma unroll
    for (int k = 0; k < 12; ++k) shA[tid + k * 1024] = kI[tid + k * 1024];
    if (tid < NQ) shPB[tid] = ((const float4*)pb)[tid];
    for (int c = tid; c < NC; c += 1024) ccnt[c] = 0u;
    for (int wI = tid; wI < WPRE; wI += 1024) {
        int base = wI * 32;
        uint32_t m = 0xFFFFFFFFu;
        if (base + 32 > PRE) m = (base >= PRE) ? 0u : (0xFFFFFFFFu >> (base + 32 - PRE));
        actw[wI] = m;
    }
    __syncthreads();

    // Phase 1: 3-way rank merge; fidx scatter, class hist, max coord (top-PRE only)
    uint32_t lmx = 0u;
    #pragma unroll
    for (int k = 0; k < 12; ++k) {
        int e = tid + k * 1024;
        ull x = shA[e];
        if (x != 0ull) {
            int run = e >> 12;
            int pos = e & (RUNSZ - 1);
            int rank = pos;
            #pragma unroll
            for (int s = 0; s < RUNS; ++s) {
                if (s != run) {
                    const ull* other = &shA[s * RUNSZ];
                    int lo = 0, hi = RUNSZ;
                    while (lo < hi) {
                        int mid = (lo + hi) >> 1;
                        if (other[mid] > x) lo = mid + 1; else hi = mid;
                    }
                    rank += lo;
                }
            }
            if (rank < PRE) {
                uint32_t f = ~(uint32_t)x;
                fidx[rank] = f;
                uint32_t q = qclamp(f / NC);
                atomicAdd(&ccnt[(f - (f / NC) * NC) % NC], 1u);
                float4 bb = shPB[q];
                float x1 = (bb.x - 0.5f * bb.z) * iw;
                float y1 = (bb.y - 0.5f * bb.w) * ih;
                float x2 = (bb.x + 0.5f * bb.z) * iw;
                float y2 = (bb.y + 0.5f * bb.w) * ih;
                uint32_t km = fkey(fmaxf(fmaxf(x1, y1), fmaxf(x2, y2)));
                if (km > lmx) lmx = km;
            }
        }
    }
    for (int off = 32; off > 0; off >>= 1) {
        uint32_t o = (uint32_t)__shfl_down((int)lmx, off, 64);
        if (o > lmx) lmx = o;
    }
    if (lane == 0) smx[tid >> 6] = lmx;
    __syncthreads();
    if (tid == 0) {
        uint32_t m = smx[0];
        for (int wv = 1; wv < 16; ++wv) if (smx[wv] > m) m = smx[wv];
        uint32_t b = (m & 0x80000000u) ? (m & 0x7FFFFFFFu) : ~m;
        sOffD = __uint_as_float(b) + 1.0f;   // max_coord + 1
        uint32_t run = 0;
        for (int c = 0; c < NC; ++c) { cstart[c] = run; cfill[c] = run; run += ccnt[c]; }
        cstart[NC] = run;
    }
    __syncthreads();
    const float offD = sOffD;

    // Phase 2: class-bucket scatter (clist aliases shA; all shA reads done)
    #pragma unroll
    for (int k = 0; k < 10; ++k) {
        int r = tid + k * 1024;
        if (r < PRE) {
            uint32_t c = fidx[r] % NC;
            uint32_t pos = atomicAdd(&cfill[c], 1u);
            if (pos < PRE) clist[pos] = (unsigned short)r;
        }
    }
    __syncthreads();

    // Phase 3: windowed greedy picks (16-wide)
    int wstart = 0;
    int pick = 0;
    while (pick < POST) {
        while (wstart < WPRE && actw[wstart] == 0u) ++wstart;   // uniform
        if (wstart >= WPRE) {
            uint32_t fi = fidx[0];
            uint32_t qi = qclamp(fi / NC);
            uint32_t ci = fi - (fi / NC) * NC;
            float4 bb = shPB[qi];
            float rx1 = (bb.x - 0.5f * bb.z) * iw;
            float ry1 = (bb.y - 0.5f * bb.w) * ih;
            float rx2 = (bb.x + 0.5f * bb.z) * iw;
            float ry2 = (bb.y + 0.5f * bb.w) * ih;
            float score = 1.0f / (1.0f + expf(-lg[(fi < NQC) ? fi : 0]));
            for (int p = pick + tid; p < POST; p += 1024) {
                out[img * POST + p] = score;
                out[BS * POST + img * POST + p] = (float)ci;
                float* ob = out + 2 * BS * POST + ((size_t)img * POST + p) * 4;
                ob[0] = rx1; ob[1] = ry1; ob[2] = rx2; ob[3] = ry2;
            }
            break;
        }

        // wave 0: parallel extraction of first <=16 active indices + candidate boxes
        if (tid < 64) {
            int wI = wstart + tid;
            uint32_t w = (wI < WPRE) ? actw[wI] : 0u;
            int c = __popc(w);
            int inc = c;
            #pragma unroll
            for (int off = 1; off < 64; off <<= 1) {
                int o = __shfl_up(inc, off, 64);
                if (tid >= off) inc += o;
            }
            int pre = inc - c;
            while (w != 0u && pre < K_WIN) {
                int b = __ffs(w) - 1; w &= w - 1u;
                s_cand[pre] = wI * 32 + b;
                ++pre;
            }
            int total = __shfl(inc, 63, 64);
            int nc = (total < K_WIN) ? total : K_WIN;
            if (tid == 0) s_ncand = nc;
            if (tid < nc) {
                int r = s_cand[tid];
                uint32_t fi = fidx[r];
                uint32_t q = qclamp(fi / NC);
                int cc = (int)(fi - (fi / NC) * NC);
                float4 bb = shPB[q];
                float x1 = (bb.x - 0.5f * bb.z) * iw;
                float y1 = (bb.y - 0.5f * bb.w) * ih;
                float x2 = (bb.x + 0.5f * bb.z) * iw;
                float y2 = (bb.y + 0.5f * bb.w) * ih;
                float o = (float)cc * offD;
                float a1 = x1 + o, b1 = y1 + o, a2 = x2 + o, b2 = y2 + o;
                s_cx1[tid] = a1; s_cy1[tid] = b1; s_cx2[tid] = a2; s_cy2[tid] = b2;
                s_car[tid] = (a2 - a1) * (b2 - b1);
                s_ccl[tid] = cc;
                s_cbs[tid] = (int)cstart[(cc >= 0 && cc < NC) ? cc : 0];
                s_cbe[tid] = (int)cstart[((cc >= 0 && cc < NC) ? cc : 0) + 1];
            }
        }
        __syncthreads();
        const int ncand = s_ncand;

        // conflict matrix: 256 pairs via 4 ballots
        ull cm[4];
        #pragma unroll
        for (int k = 0; k < 4; ++k) {
            int p = k * 64 + lane;
            int pj = p >> 4, pm = p & 15;
            bool conf = false;
            if (pm < pj && pj < ncand) {
                float xx1 = fmaxf(s_cx1[pm], s_cx1[pj]);
                float yy1 = fmaxf(s_cy1[pm], s_cy1[pj]);
                float xx2 = fminf(s_cx2[pm], s_cx2[pj]);
                float yy2 = fminf(s_cy2[pm], s_cy2[pj]);
                float inter = fmaxf(xx2 - xx1, 0.0f) * fmaxf(yy2 - yy1, 0.0f);
                float uni = (s_car[pm] + s_car[pj]) - inter;
                float iou = inter / fmaxf(uni, 1e-9f);
                conf = !(iou <= 0.7f);
            }
            cm[k] = __ballot(conf);
        }
        uint32_t accMask = 0u;
        int A = 0;
        const int maxA = POST - pick;
        #pragma unroll
        for (int j = 0; j < K_WIN; ++j) {
            uint32_t row = (uint32_t)(cm[j >> 2] >> ((j & 3) * 16)) & 0xFFFFu;
            if (j < ncand && A < maxA && ((row & accMask) == 0u)) { accMask |= (1u << j); ++A; }
        }

        // outputs (pick order = candidate order among accepted)
        #pragma unroll
        for (int j = 0; j < K_WIN; ++j) {
            if ((accMask >> j) & 1u) {
                int ord = __popc(accMask & ((1u << j) - 1u));
                if (tid == ord) {
                    int r = s_cand[j];
                    uint32_t fi = fidx[r];
                    uint32_t qi = qclamp(fi / NC);
                    uint32_t ci = fi - (fi / NC) * NC;
                    float4 bb = shPB[qi];
                    float rx1 = (bb.x - 0.5f * bb.z) * iw;
                    float ry1 = (bb.y - 0.5f * bb.w) * ih;
                    float rx2 = (bb.x + 0.5f * bb.z) * iw;
                    float ry2 = (bb.y + 0.5f * bb.w) * ih;
                    float score = 1.0f / (1.0f + expf(-lg[(fi < NQC) ? fi : 0]));
                    int p = pick + ord;
                    out[img * POST + p] = score;
                    out[BS * POST + img * POST + p] = (float)ci;
                    float* ob = out + 2 * BS * POST + ((size_t)img * POST + p) * 4;
                    ob[0] = rx1; ob[1] = ry1; ob[2] = rx2; ob[3] = ry2;
                }
            }
        }

        // flattened suppression over (accepted j, bucket item)
        int startj[K_WIN];
        int tot = 0;
        #pragma unroll
        for (int j = 0; j < K_WIN; ++j) {
            startj[j] = tot;
            if ((accMask >> j) & 1u) tot += s_cbe[j] - s_cbs[j];
        }
        for (int t2 = tid; t2 < tot; t2 += 1024) {
            int j = 0;
            #pragma unroll
            for (int jj = 1; jj < K_WIN; ++jj) if (startj[jj] <= t2) j = jj;
            int r2 = clist[s_cbs[j] + (t2 - startj[j])];
            if (actw[r2 >> 5] & (1u << (r2 & 31))) {
                float o = (float)s_ccl[j] * offD;
                uint32_t f2 = fidx[r2];
                uint32_t q2 = qclamp(f2 / NC);
                float4 bb = shPB[q2];
                float jx1 = (bb.x - 0.5f * bb.z) * iw + o;
                float jy1 = (bb.y - 0.5f * bb.w) * ih + o;
                float jx2 = (bb.x + 0.5f * bb.z) * iw + o;
                float jy2 = (bb.y + 0.5f * bb.w) * ih + o;
                float arj = (jx2 - jx1) * (jy2 - jy1);
                float xx1 = fmaxf(s_cx1[j], jx1);
                float yy1 = fmaxf(s_cy1[j], jy1);
                float xx2 = fminf(s_cx2[j], jx2);
                float yy2 = fminf(s_cy2[j], jy2);
                float inter = fmaxf(xx2 - xx1, 0.0f) * fmaxf(yy2 - yy1, 0.0f);
                float uni = (s_car[j] + arj) - inter;
                float iou = inter / fmaxf(uni, 1e-9f);
                if (!(iou <= 0.7f)) atomicAnd(&actw[r2 >> 5], ~(1u << (r2 & 31)));
            }
        }
        pick += A;
        __syncthreads();
    }
}

extern "C" void kernel_launch(void* const* d_in, const int* in_sizes, int n_in,
                              void* d_out, int out_size, void* d_ws, size_t ws_size,
                              hipStream_t stream) {
    const float* logits = (const float*)d_in[0];
    const float* boxes  = (const float*)d_in[1];
    const float* tsizes = (const float*)d_in[2];
    float* out = (float*)d_out;

    char* ws = (char*)d_ws;
    uint32_t* thr = (uint32_t*)(ws + WS_THR);
    ull* keys = (ull*)(ws + WS_KEYS);

    k_select<<<BS, 1024, 0, stream>>>(logits, thr);
    k_sortcompact<<<dim3(RUNS, BS), 1024, 0, stream>>>(logits, thr, keys);
    k_nms<<<BS, 1024, 0, stream>>>(keys, logits, boxes, tsizes, out);
}